// Round 8
// baseline (2237.792 us; speedup 1.0000x reference)
//
#include <hip/hip_runtime.h>
#include <hip/hip_fp16.h>
#include <math.h>

#define EPSB 1e-5f

__device__ __forceinline__ float fsig(float x){ x = fminf(fmaxf(x,-30.f),30.f); return 1.f/(1.f+__expf(-x)); }
__device__ __forceinline__ float ftanh(float x){ x = fminf(fmaxf(x,-15.f),15.f); float t = __expf(2.f*x); return __fdividef(t-1.f, t+1.f); }

typedef _Float16 h2_t __attribute__((ext_vector_type(2)));
__device__ __forceinline__ h2_t as_h2(unsigned u){ union{unsigned x; h2_t h;} c; c.x=u; return c.h; }
__device__ __forceinline__ float dot2f(unsigned w, unsigned h, float acc){
#if __has_builtin(__builtin_amdgcn_fdot2)
  return __builtin_amdgcn_fdot2(as_h2(w), as_h2(h), acc, false);
#else
  __half2 hw = *(__half2*)&w, hh = *(__half2*)&h;
  return acc + __low2float(hw)*__low2float(hh) + __high2float(hw)*__high2float(hh);
#endif
}
__device__ __forceinline__ float2 h2f2(unsigned u){ __half2 h = *(__half2*)&u; return __half22float2(h); }

// agent-scope (LLC-coherent) helpers; all RELAXED (R5: release fence => L2 wbinv).
__device__ __forceinline__ void ag_store(float* p, float v){
  __hip_atomic_store(p, v, __ATOMIC_RELAXED, __HIP_MEMORY_SCOPE_AGENT);
}
__device__ __forceinline__ float ag_load(const float* p){
  return __hip_atomic_load(p, __ATOMIC_RELAXED, __HIP_MEMORY_SCOPE_AGENT);
}

// ---------------- transpose: dst[c*R+r] = src[r*C+c] ----------------
__global__ __launch_bounds__(256) void k_transpose(float* __restrict__ dst, const float* __restrict__ src, int R, int C){
  int t = blockIdx.x*256 + threadIdx.x;
  if (t >= R*C) return;
  int r = t / C, c = t - r*C;
  dst[c*R + r] = src[t];
}

// ---------------- pack fp32 [N][K] (out-major) -> f16x8 uint4 [K/8][dstStride] ----------------
__global__ __launch_bounds__(256) void k_packw8(uint4* __restrict__ dst, const float* __restrict__ src,
    int N, int K, int dstStride, int colOff){
  int t = blockIdx.x*256 + threadIdx.x;
  int total = N*(K >> 3);
  if (t >= total) return;
  int o = t % N, k8 = t / N;
  const float* s = src + (size_t)o*K + 8*k8;
  unsigned r[4];
  #pragma unroll
  for (int q = 0; q < 4; ++q){
    __half a = __float2half_rn(s[2*q]), b = __float2half_rn(s[2*q+1]);
    r[q] = (unsigned)(*(unsigned short*)&a) | ((unsigned)(*(unsigned short*)&b) << 16);
  }
  dst[(size_t)k8*dstStride + colOff + o] = make_uint4(r[0], r[1], r[2], r[3]);
}

// ---------------- embedding ----------------
__global__ __launch_bounds__(256) void k_embed(float* __restrict__ tE, const float* __restrict__ emb, const int* __restrict__ idx){
  int t = blockIdx.x*256 + threadIdx.x;
  int b = t >> 12, r = t & 4095, ch = r >> 5, l = r & 31;
  tE[t] = emb[idx[b*32 + l]*128 + ch];
}

// ---------------- text conv1d (k=3, pad=1) + relu ----------------
__global__ __launch_bounds__(256) void k_conv1d(const float* __restrict__ in, const float* __restrict__ w,
    const float* __restrict__ bias, float* __restrict__ out, int Cin, int Cout){
  __shared__ float inL[8192];
  int b = blockIdx.y, tid = threadIdx.x;
  int n = Cin*32;
  for (int i = tid; i < n; i += 256) inL[i] = in[(size_t)b*n + i];
  __syncthreads();
  int u = blockIdx.x*256 + tid;
  int co = u >> 2, l0 = (u & 3)*8;
  float acc[8];
  #pragma unroll
  for (int l = 0; l < 8; ++l) acc[l] = 0.f;
  for (int ci = 0; ci < Cin; ++ci){
    float rin[10];
    #pragma unroll
    for (int ii = 0; ii < 10; ++ii){
      int p = l0 - 1 + ii;
      rin[ii] = (p >= 0 && p < 32) ? inL[ci*32 + p] : 0.f;
    }
    const float* wp = w + ((size_t)co*Cin + ci)*3;
    float w0 = wp[0], w1 = wp[1], w2 = wp[2];
    #pragma unroll
    for (int l = 0; l < 8; ++l) acc[l] += rin[l]*w0 + rin[l+1]*w1 + rin[l+2]*w2;
  }
  float bb = bias ? bias[co] : 0.f;
  #pragma unroll
  for (int l = 0; l < 8; ++l){
    float v = acc[l] + bb;
    out[((size_t)b*Cout + co)*32 + l0 + l] = v > 0.f ? v : 0.f;
  }
}

// ---------------- text bn ----------------
__global__ __launch_bounds__(256) void k_bn_text(float* __restrict__ x, const float* __restrict__ g, const float* __restrict__ be, int C){
  __shared__ float s1[256], s2[256];
  __shared__ float sc[2];
  int c = blockIdx.x, tid = threadIdx.x;
  float sum = 0.f, ss = 0.f;
  for (int i = tid; i < 2048; i += 256){
    int b = i >> 5, l = i & 31;
    float v = x[((size_t)b*C + c)*32 + l];
    sum += v; ss += v*v;
  }
  s1[tid] = sum; s2[tid] = ss;
  __syncthreads();
  for (int off = 128; off; off >>= 1){
    if (tid < off){ s1[tid] += s1[tid+off]; s2[tid] += s2[tid+off]; }
    __syncthreads();
  }
  if (tid == 0){
    float mean = s1[0]*(1.f/2048.f);
    float var  = s2[0]*(1.f/2048.f) - mean*mean;
    float rs = rsqrtf(var + EPSB);
    sc[0] = g[c]*rs;
    sc[1] = be[c] - mean*g[c]*rs;
  }
  __syncthreads();
  float a = sc[0], bsh = sc[1];
  for (int i = tid; i < 2048; i += 256){
    int b = i >> 5, l = i & 31;
    size_t o = ((size_t)b*C + c)*32 + l;
    x[o] = x[o]*a + bsh;
  }
}

// ---------------- conv bn partial + finalize ----------------
__global__ __launch_bounds__(256) void k_bn_partial(const float* __restrict__ x, float* __restrict__ sums, int C, int S, int split){
  __shared__ float s1[256], s2[256];
  int c = blockIdx.x / split, chunk = blockIdx.x - c*split;
  int tid = threadIdx.x;
  int n = 64*S, per = n/split, i0 = chunk*per;
  float sum = 0.f, ss = 0.f;
  for (int i = i0 + tid; i < i0 + per; i += 256){
    int b = i / S, s = i - b*S;
    float v = x[((size_t)b*C + c)*S + s];
    sum += v; ss += v*v;
  }
  s1[tid] = sum; s2[tid] = ss;
  __syncthreads();
  for (int off = 128; off; off >>= 1){
    if (tid < off){ s1[tid] += s1[tid+off]; s2[tid] += s2[tid+off]; }
    __syncthreads();
  }
  if (tid == 0){
    atomicAdd(&sums[c], s1[0]);
    atomicAdd(&sums[C + c], s2[0]);
  }
}

__global__ void k_bn_finalize(const float* __restrict__ sums, const float* __restrict__ g, const float* __restrict__ be,
    float* __restrict__ scale, float* __restrict__ shift, int C, int S){
  int c = blockIdx.x*64 + threadIdx.x;
  if (c >= C) return;
  float n = 64.f*(float)S;
  float mean = sums[c]/n;
  float var  = sums[C+c]/n - mean*mean;
  float rs = rsqrtf(var + EPSB);
  scale[c] = g[c]*rs;
  shift[c] = be[c] - mean*g[c]*rs;
}

// ---------------- conv1 ----------------
__global__ __launch_bounds__(256) void k_conv1(const float* __restrict__ in, const float* __restrict__ wT1,
    const float* __restrict__ bias, float* __restrict__ out){
  __shared__ float tile[3888];
  int z = blockIdx.x, yq = blockIdx.y, b = blockIdx.z, tid = threadIdx.x;
  int cog = tid & 15, posg = tid >> 4;
  int yy = posg >> 2, xq = posg & 3;
  for (int i = tid; i < 3564; i += 256){
    int r = i/33, col = i - r*33;
    int ci = r/27, rr = r - 27*ci, dz = rr/9, iyl = rr - 9*dz;
    int iz = 2*z - 1 + dz;
    int iy = 8*yq - 1 + iyl;
    int ix = (col < 16) ? 2*col : 2*(col-16)-1;
    float v = 0.f;
    if (iz >= 0 && iz < 32 && iy >= 0 && ix >= 0)
      v = in[(((size_t)b*4 + ci)*32 + iz)*1024 + iy*32 + ix];
    tile[r*36 + col] = v;
  }
  __syncthreads();
  float acc[4][4];
  #pragma unroll
  for (int c = 0; c < 4; ++c){
    #pragma unroll
    for (int x = 0; x < 4; ++x) acc[c][x] = 0.f;
  }
  #pragma unroll 1
  for (int ci = 0; ci < 4; ++ci){
    #pragma unroll
    for (int dz = 0; dz < 3; ++dz){
      #pragma unroll
      for (int dy = 0; dy < 3; ++dy){
        int row = ci*972 + dz*324 + (2*yy + dy)*36;
        float4 ev = *(const float4*)&tile[row + 4*xq];
        float4 od = *(const float4*)&tile[row + 16 + 4*xq];
        float od4 = tile[row + 20 + 4*xq];
        const float* wp = wT1 + (ci*27 + dz*9 + dy*3)*64 + 4*cog;
        float4 w0 = *(const float4*)(wp);
        float4 w1 = *(const float4*)(wp + 64);
        float4 w2 = *(const float4*)(wp + 128);
        float iv0[4] = {od.x, od.y, od.z, od.w};
        float iv1[4] = {ev.x, ev.y, ev.z, ev.w};
        float iv2[4] = {od.y, od.z, od.w, od4};
        float wa0[4] = {w0.x,w0.y,w0.z,w0.w};
        float wa1[4] = {w1.x,w1.y,w1.z,w1.w};
        float wa2[4] = {w2.x,w2.y,w2.z,w2.w};
        #pragma unroll
        for (int c = 0; c < 4; ++c){
          #pragma unroll
          for (int x = 0; x < 4; ++x)
            acc[c][x] += wa0[c]*iv0[x] + wa1[c]*iv1[x] + wa2[c]*iv2[x];
        }
      }
    }
  }
  float4 bi = *(const float4*)&bias[4*cog];
  float ba[4] = {bi.x,bi.y,bi.z,bi.w};
  int y = yq*4 + yy;
  #pragma unroll
  for (int c = 0; c < 4; ++c){
    int co = 4*cog + c;
    float4 o;
    float* op = (float*)&o;
    #pragma unroll
    for (int x = 0; x < 4; ++x){
      float v = acc[c][x] + ba[c];
      op[x] = v > 0.f ? v : 0.f;
    }
    *(float4*)&out[(((size_t)b*64 + co)*16 + z)*256 + y*16 + 4*xq] = o;
  }
}

// ---------------- conv2: ci-chunk 8 -> 33 KB LDS -> ~3 blocks/CU ----------------
__global__ __launch_bounds__(256) void k_conv2(const float* __restrict__ x1, const float* __restrict__ wT2,
    const float* __restrict__ bias, const float* __restrict__ scale, const float* __restrict__ shift,
    float* __restrict__ out){
  __shared__ float tile[8160];    // 8ci * 3dz * 17iy * 20
  __shared__ float sclL[64], shfL[64];
  int z = blockIdx.x, coh = blockIdx.y, b = blockIdx.z, tid = threadIdx.x;
  int cog = tid & 15, posg = tid >> 4;
  int y = posg >> 1, xq = posg & 1;
  if (tid < 64){ sclL[tid] = scale[tid]; shfL[tid] = shift[tid]; }
  float acc[4][4];
  #pragma unroll
  for (int c = 0; c < 4; ++c){
    #pragma unroll
    for (int x = 0; x < 4; ++x) acc[c][x] = 0.f;
  }
  for (int ci0 = 0; ci0 < 64; ci0 += 8){
    __syncthreads();
    for (int i = tid; i < 6936; i += 256){
      int q = i/289, rem = i - q*289;
      int iyr = rem/17, col = rem - iyr*17;
      int ci = q/3, dz = q - 3*ci;
      int iz = 2*z - 1 + dz;
      int iy = iyr - 1;
      int ix = (col < 8) ? 2*col : 2*(col-8)-1;
      int cc = ci0 + ci;
      float v = 0.f;
      if (iz >= 0 && iz < 16 && iy >= 0 && ix >= 0)
        v = x1[(((size_t)b*64 + cc)*16 + iz)*256 + iy*16 + ix]*sclL[cc] + shfL[cc];
      tile[q*340 + iyr*20 + col] = v;
    }
    __syncthreads();
    #pragma unroll 1
    for (int ci = 0; ci < 8; ++ci){
      const float* wp = wT2 + ((size_t)(ci0+ci)*27)*128 + coh*64 + 4*cog;
      #pragma unroll
      for (int dz = 0; dz < 3; ++dz){
        #pragma unroll
        for (int dy = 0; dy < 3; ++dy){
          int row = ci*1020 + dz*340 + (2*y + dy)*20;
          float4 ev = *(const float4*)&tile[row + 4*xq];
          float4 od = *(const float4*)&tile[row + 8 + 4*xq];
          float od4 = tile[row + 12 + 4*xq];
          const float* wq = wp + (dz*9 + dy*3)*128;
          float4 w0 = *(const float4*)(wq);
          float4 w1 = *(const float4*)(wq + 128);
          float4 w2 = *(const float4*)(wq + 256);
          float iv0[4] = {od.x, od.y, od.z, od.w};
          float iv1[4] = {ev.x, ev.y, ev.z, ev.w};
          float iv2[4] = {od.y, od.z, od.w, od4};
          float wa0[4] = {w0.x,w0.y,w0.z,w0.w};
          float wa1[4] = {w1.x,w1.y,w1.z,w1.w};
          float wa2[4] = {w2.x,w2.y,w2.z,w2.w};
          #pragma unroll
          for (int c = 0; c < 4; ++c){
            #pragma unroll
            for (int x = 0; x < 4; ++x)
              acc[c][x] += wa0[c]*iv0[x] + wa1[c]*iv1[x] + wa2[c]*iv2[x];
          }
        }
      }
    }
  }
  float4 bi = *(const float4*)&bias[coh*64 + 4*cog];
  float ba[4] = {bi.x,bi.y,bi.z,bi.w};
  #pragma unroll
  for (int c = 0; c < 4; ++c){
    int co = coh*64 + 4*cog + c;
    float4 o;
    float* op = (float*)&o;
    #pragma unroll
    for (int x = 0; x < 4; ++x){
      float v = acc[c][x] + ba[c];
      op[x] = v > 0.f ? v : 0.f;
    }
    *(float4*)&out[(((size_t)b*128 + co)*8 + z)*64 + y*8 + 4*xq] = o;
  }
}

// ---------------- conv3: 256-thr blocks, 8 co-groups, ci-chunk 8 -> 31 KB LDS ----------------
__global__ __launch_bounds__(256) void k_conv3(const float* __restrict__ x2, const float* __restrict__ wT3,
    const float* __restrict__ bias, const float* __restrict__ scale, const float* __restrict__ shift,
    float* __restrict__ out){
  __shared__ float tile[7776];    // 8ci * 9iz * 9iy * 12
  __shared__ float sclL[128], shfL[128];
  int coq = blockIdx.x, b = blockIdx.y, tid = threadIdx.x;
  int cog = tid & 7, posg = tid >> 3;      // 8 co-groups x 32 pos-groups
  int zz = posg >> 3, y = (posg >> 1) & 3, xh = posg & 1;
  if (tid < 128){ sclL[tid] = scale[tid]; shfL[tid] = shift[tid]; }
  float acc[4][2];
  #pragma unroll
  for (int c = 0; c < 4; ++c){ acc[c][0] = 0.f; acc[c][1] = 0.f; }
  for (int ci0 = 0; ci0 < 128; ci0 += 8){
    __syncthreads();
    for (int i = tid; i < 5832; i += 256){
      int ci = i/729, rem = i - ci*729;
      int izr = rem/81, rem2 = rem - izr*81;
      int iyr = rem2/9, col = rem2 - iyr*9;
      int iz = izr - 1, iy = iyr - 1;
      int ix = (col < 4) ? 2*col : 2*(col-4)-1;
      int cc = ci0 + ci;
      float v = 0.f;
      if (iz >= 0 && iy >= 0 && ix >= 0)
        v = x2[((size_t)b*128 + cc)*512 + iz*64 + iy*8 + ix]*sclL[cc] + shfL[cc];
      tile[ci*972 + izr*108 + iyr*12 + col] = v;
    }
    __syncthreads();
    #pragma unroll 1
    for (int ci = 0; ci < 8; ++ci){
      const float* wp = wT3 + ((size_t)(ci0+ci)*27)*256 + coq*32 + 4*cog;
      #pragma unroll
      for (int dz = 0; dz < 3; ++dz){
        #pragma unroll
        for (int dy = 0; dy < 3; ++dy){
          int row = ci*972 + (2*zz + dz)*108 + (2*y + dy)*12;
          float2 ev = *(const float2*)&tile[row + 2*xh];
          float2 od = *(const float2*)&tile[row + 4 + 2*xh];
          float od1 = tile[row + 6 + 2*xh];
          const float* wq = wp + (dz*9 + dy*3)*256;
          float4 w0 = *(const float4*)(wq);
          float4 w1 = *(const float4*)(wq + 256);
          float4 w2 = *(const float4*)(wq + 512);
          float iv0[2] = {od.x, od.y};
          float iv1[2] = {ev.x, ev.y};
          float iv2[2] = {od.y, od1};
          float wa0[4] = {w0.x,w0.y,w0.z,w0.w};
          float wa1[4] = {w1.x,w1.y,w1.z,w1.w};
          float wa2[4] = {w2.x,w2.y,w2.z,w2.w};
          #pragma unroll
          for (int c = 0; c < 4; ++c){
            #pragma unroll
            for (int x = 0; x < 2; ++x)
              acc[c][x] += wa0[c]*iv0[x] + wa1[c]*iv1[x] + wa2[c]*iv2[x];
          }
        }
      }
    }
  }
  float4 bi = *(const float4*)&bias[coq*32 + 4*cog];
  float ba[4] = {bi.x,bi.y,bi.z,bi.w};
  #pragma unroll
  for (int c = 0; c < 4; ++c){
    int co = coq*32 + 4*cog + c;
    float2 o;
    float v0 = acc[c][0] + ba[c], v1 = acc[c][1] + ba[c];
    o.x = v0 > 0.f ? v0 : 0.f;
    o.y = v1 > 0.f ? v1 : 0.f;
    *(float2*)&out[((size_t)b*256 + co)*64 + zz*16 + y*4 + 2*xh] = o;
  }
}

// ---------------- bn3 apply ----------------
__global__ __launch_bounds__(256) void k_bn_apply(float* __restrict__ x, const float* __restrict__ scale, const float* __restrict__ shift){
  int i = blockIdx.x*256 + threadIdx.x;
  int c = (i >> 6) & 255;
  x[i] = x[i]*scale[c] + shift[c];
}

// ---------------- x-projections ----------------
__global__ __launch_bounds__(256) void k_xproj(const float* __restrict__ tD,
    const float* __restrict__ wihT, const float* __restrict__ wxgT,
    const float* __restrict__ bih, const float* __restrict__ bhh,
    const float* __restrict__ bxg, const float* __restrict__ bhg,
    float* __restrict__ xih, float* __restrict__ xg){
  __shared__ float xr[8][256];
  int b = blockIdx.x >> 2, t0 = (blockIdx.x & 3)*8, tid = threadIdx.x;
  for (int i = tid; i < 2048; i += 256){
    int tt = i >> 8, c = i & 255;
    xr[tt][c] = tD[((size_t)b*256 + c)*32 + t0 + tt];
  }
  __syncthreads();
  float4 bi = ((const float4*)bih)[tid];
  float4 b2 = ((const float4*)bhh)[tid];
  float4 binit = make_float4(bi.x+b2.x, bi.y+b2.y, bi.z+b2.z, bi.w+b2.w);
  float4 a[8];
  #pragma unroll
  for (int tt = 0; tt < 8; ++tt) a[tt] = binit;
  const float4* Wq = (const float4*)wihT;
  for (int k = 0; k < 256; ++k){
    float4 w = Wq[k*256 + tid];
    #pragma unroll
    for (int tt = 0; tt < 8; ++tt){
      float xv = xr[tt][k];
      a[tt].x += xv*w.x; a[tt].y += xv*w.y; a[tt].z += xv*w.z; a[tt].w += xv*w.w;
    }
  }
  #pragma unroll
  for (int tt = 0; tt < 8; ++tt)
    ((float4*)xih)[((size_t)(b*32 + t0 + tt))*256 + tid] = a[tt];
  if (tid < 64){
    float4 bg = ((const float4*)bxg)[tid];
    float4 bg2 = ((const float4*)bhg)[tid];
    float4 ginit = make_float4(bg.x+bg2.x, bg.y+bg2.y, bg.z+bg2.z, bg.w+bg2.w);
    float4 g[8];
    #pragma unroll
    for (int tt = 0; tt < 8; ++tt) g[tt] = ginit;
    const float4* Wg = (const float4*)wxgT;
    for (int k = 0; k < 256; ++k){
      float4 w = Wg[k*64 + tid];
      #pragma unroll
      for (int tt = 0; tt < 8; ++tt){
        float xv = xr[tt][k];
        g[tt].x += xv*w.x; g[tt].y += xv*w.y; g[tt].z += xv*w.z; g[tt].w += xv*w.w;
      }
    }
    #pragma unroll
    for (int tt = 0; tt < 8; ++tt)
      ((float4*)xg)[((size_t)(b*32 + t0 + tt))*64 + tid] = g[tt];
  }
}

// ---------------- vproj (f16 output) ----------------
__global__ __launch_bounds__(256) void k_vproj(const float* __restrict__ V, const float* __restrict__ wvT,
    const float* __restrict__ bv, unsigned* __restrict__ vprojH){
  __shared__ float Vc[8][256];
  int n0 = blockIdx.x*8, b = blockIdx.y, tid = threadIdx.x;
  for (int i = tid; i < 2048; i += 256){
    int nn = i >> 8, c = i & 255;
    Vc[nn][c] = V[((size_t)b*256 + c)*64 + n0 + nn];
  }
  __syncthreads();
  int o0 = 2*tid;
  float2 bb = *(const float2*)&bv[o0];
  float a0[8], a1[8];
  #pragma unroll
  for (int nn = 0; nn < 8; ++nn){ a0[nn] = bb.x; a1[nn] = bb.y; }
  for (int k = 0; k < 256; ++k){
    float2 w = *(const float2*)&wvT[k*512 + o0];
    #pragma unroll
    for (int nn = 0; nn < 8; ++nn){
      float vv = Vc[nn][k];
      a0[nn] += vv*w.x; a1[nn] += vv*w.y;
    }
  }
  #pragma unroll
  for (int nn = 0; nn < 8; ++nn){
    __half2 p = __floats2half2_rn(a0[nn], a1[nn]);
    vprojH[((size_t)(b*64 + n0 + nn))*256 + tid] = *(unsigned*)&p;
  }
}

// ---------------- 4-way K-split scan, XCD-aware q, vproj in LDS, 1 sync/step ----------------
__global__ __launch_bounds__(1024) void k_scan4(
    const float* __restrict__ V,
    const unsigned* __restrict__ vprojH,
    const float* __restrict__ xih,
    const float* __restrict__ xg,
    const uint4* __restrict__ WA,   // whh f16x8 [32][1024]
    const uint4* __restrict__ WG,   // whg f16x8 [32][256]
    const uint4* __restrict__ WC,   // wh | ws f16x8 [32][1024]
    const float* __restrict__ bh,
    const float* __restrict__ bs,
    const float* __restrict__ wo,
    const float* __restrict__ bo,
    const float* __restrict__ sow, const float* __restrict__ sob,
    const float* __restrict__ tow1, const float* __restrict__ tob1,
    const float* __restrict__ tow2, const float* __restrict__ tob2,
    float* __restrict__ exch1,      // [64][2][4][1280]
    unsigned* __restrict__ cnts,    // [64][32][2] (slot 0 used)
    float* __restrict__ out)
{
  __shared__ float VL[16384];
  __shared__ unsigned vprojL[16640];
  __shared__ __align__(16) float gatesL[1024];
  __shared__ float hgL[256];
  __shared__ float hL[256], hnewL[256], sentL[256];
  __shared__ __align__(16) unsigned hP[128];
  __shared__ __align__(16) unsigned hsP[256];
  __shared__ float hpSw[528], spSw[528], woSw[528];
  __shared__ float bhbsL[1024];
  __shared__ float red[1040];
  __shared__ float szred[576];
  __shared__ float wL[65];
  __shared__ float ctxmL[256], tmpL[256];

  int bid = blockIdx.x;
  int b = bid >> 2, q = bid & 3;       // XCD-aware: q constant per XCD
  int tid = threadIdx.x;
  int k80 = q*8;

  for (int i = tid; i < 16384; i += 1024){
    int c = i >> 6, n2 = i & 63;
    VL[n2*256 + c] = V[((size_t)b*256 + c)*64 + n2];
  }
  for (int i = tid; i < 16384; i += 1024)
    vprojL[(i >> 8)*260 + (i & 255)] = vprojH[(size_t)b*16384 + i];
  if (tid < 512) woSw[(tid>>5)*33 + (tid&31)] = wo[tid];
  bhbsL[tid] = (tid < 512) ? bh[tid] : bs[tid-512];
  if (tid < 128) hP[tid] = 0u;
  float creg0 = 0.f, creg1 = 0.f, ctxs0 = 0.f, ctxs1 = 0.f;
  float bo0 = bo[0];
  __syncthreads();

  for (int t = 0; t < 32; ++t){
    int par = t & 1;
    float* e1 = exch1 + (((size_t)b*2 + par)*4 + q)*1280;
    unsigned* c1 = cnts + (b*32 + t)*2;

    // ---- A: K-quarter partials for gates (all threads) and hg (tid<256) ----
    float mineGates, mineG = 0.f;
    {
      float a0 = 0.f, a1 = 0.f, a2 = 0.f, a3 = 0.f;
      #pragma unroll
      for (int i = 0; i < 8; ++i){
        uint4 w = WA[(size_t)(k80+i)*1024 + tid];
        uint4 hh = *(const uint4*)&hP[4*(k80+i)];
        a0 = dot2f(w.x, hh.x, a0);
        a1 = dot2f(w.y, hh.y, a1);
        a2 = dot2f(w.z, hh.z, a2);
        a3 = dot2f(w.w, hh.w, a3);
      }
      mineGates = (a0+a1)+(a2+a3);
      ag_store(&e1[tid], mineGates);
    }
    if (tid < 256){
      float g0 = 0.f, g1 = 0.f, g2 = 0.f, g3 = 0.f;
      #pragma unroll
      for (int i = 0; i < 8; ++i){
        uint4 w = WG[(size_t)(k80+i)*256 + tid];
        uint4 hh = *(const uint4*)&hP[4*(k80+i)];
        g0 = dot2f(w.x, hh.x, g0);
        g1 = dot2f(w.y, hh.y, g1);
        g2 = dot2f(w.z, hh.z, g2);
        g3 = dot2f(w.w, hh.w, g3);
      }
      mineG = (g0+g1)+(g2+g3);
      ag_store(&e1[1024 + tid], mineG);
    }
    __syncthreads();              // drains vmcnt(0): partial stores visible at LLC
    if (tid == 0){
      __hip_atomic_fetch_add(c1, 1u, __ATOMIC_RELAXED, __HIP_MEMORY_SCOPE_AGENT);
      while (__hip_atomic_load(c1, __ATOMIC_RELAXED, __HIP_MEMORY_SCOPE_AGENT) < 4u)
        __builtin_amdgcn_s_sleep(2);
    }
    __syncthreads();
    // ---- gather full gates / hg (own quarter from register) ----
    {
      const float* basep = exch1 + (((size_t)b*2 + par)*4)*1280;
      float s = xih[((size_t)(b*32 + t))*1024 + tid] + mineGates;
      #pragma unroll
      for (int qq = 0; qq < 4; ++qq){
        if (qq == q) continue;                 // block-uniform branch
        s += ag_load(basep + qq*1280 + tid);
      }
      gatesL[tid] = s;
      if (tid < 256){
        float g = xg[((size_t)(b*32 + t))*256 + tid] + mineG;
        #pragma unroll
        for (int qq = 0; qq < 4; ++qq){
          if (qq == q) continue;
          g += ag_load(basep + qq*1280 + 1024 + tid);
        }
        hgL[tid] = g;
      }
    }
    __syncthreads();
    // ---- B: LSTM cell (tid<128, cells 2j,2j+1) ----
    if (tid < 128){
      int j = tid;
      float hg0 = hgL[2*j], hg1 = hgL[2*j+1];
      const float2* gl = (const float2*)gatesL;
      float2 gi = gl[j], gf = gl[128+j], gg = gl[256+j], go = gl[384+j];
      float i0 = fsig(gi.x), i1 = fsig(gi.y);
      float f0 = fsig(gf.x), f1 = fsig(gf.y);
      float g0 = ftanh(gg.x), g1 = ftanh(gg.y);
      float o0 = fsig(go.x), o1 = fsig(go.y);
      float c0 = f0*creg0 + i0*g0; creg0 = c0;
      float c1v = f1*creg1 + i1*g1; creg1 = c1v;
      float tc0 = ftanh(c0), tc1 = ftanh(c1v);
      float hn0 = o0*tc0, hn1 = o1*tc1;
      float s0 = fsig(hg0)*tc0, s1 = fsig(hg1)*tc1;
      hnewL[2*j] = hn0; hnewL[2*j+1] = hn1;
      sentL[2*j] = s0;  sentL[2*j+1] = s1;
      __half2 ph = __floats2half2_rn(hn0, hn1); hsP[j] = *(unsigned*)&ph;
      __half2 ps = __floats2half2_rn(s0, s1);   hsP[128+j] = *(unsigned*)&ps;
    }
    __syncthreads();
    // ---- C: full-K hp (o<512, h_new) | sp (o>=512, sent), local (WC L2-resident) ----
    {
      int o = tid;
      int base = (o < 512) ? 0 : 128;
      float a0 = bhbsL[o], a1 = 0.f, a2 = 0.f, a3 = 0.f;
      #pragma unroll 8
      for (int k8 = 0; k8 < 32; ++k8){
        uint4 w = WC[(size_t)k8*1024 + o];
        uint4 hh = *(const uint4*)&hsP[base + 4*k8];
        a0 = dot2f(w.x, hh.x, a0);
        a1 = dot2f(w.y, hh.y, a1);
        a2 = dot2f(w.z, hh.z, a2);
        a3 = dot2f(w.w, hh.w, a3);
      }
      float acc = (a0+a1)+(a2+a3);
      int oo = o & 511;
      int r = (oo>>5)*33 + (oo&31);
      if (o < 512) hpSw[r] = acc; else spSw[r] = acc;
    }
    __syncthreads();
    // ---- D: z partials (vproj from LDS) + sz terms ----
    {
      int n2 = tid >> 4, seg = tid & 15;
      const unsigned* vp = &vprojL[n2*260 + seg*16];
      float a = 0.f;
      #pragma unroll
      for (int qq = 0; qq < 4; ++qq){
        uint4 v = *(const uint4*)&vp[4*qq];
        int r = seg*33 + 8*qq;
        float2 f0 = h2f2(v.x), f1 = h2f2(v.y), f2 = h2f2(v.z), f3 = h2f2(v.w);
        a += ftanh(f0.x + hpSw[r  ])*woSw[r  ];
        a += ftanh(f0.y + hpSw[r+1])*woSw[r+1];
        a += ftanh(f1.x + hpSw[r+2])*woSw[r+2];
        a += ftanh(f1.y + hpSw[r+3])*woSw[r+3];
        a += ftanh(f2.x + hpSw[r+4])*woSw[r+4];
        a += ftanh(f2.y + hpSw[r+5])*woSw[r+5];
        a += ftanh(f3.x + hpSw[r+6])*woSw[r+6];
        a += ftanh(f3.y + hpSw[r+7])*woSw[r+7];
      }
      red[seg*65 + n2] = a;
      if (tid < 512){
        int r = (tid>>5)*33 + (tid&31);
        szred[(tid&63)*9 + (tid>>6)] = ftanh(spSw[r] + hpSw[r])*woSw[r];
      }
    }
    __syncthreads();
    // ---- E: fold + softmax over 65 (wave 0) ----
    if (tid < 64){
      float zi = bo0;
      #pragma unroll
      for (int i = 0; i < 16; ++i) zi += red[i*65 + tid];
      float szp = 0.f;
      #pragma unroll
      for (int i = 0; i < 8; ++i) szp += szred[tid*9 + i];
      #pragma unroll
      for (int off = 32; off; off >>= 1) szp += __shfl_xor(szp, off, 64);
      float sz = szp + bo0;
      float m = zi;
      #pragma unroll
      for (int off = 32; off; off >>= 1) m = fmaxf(m, __shfl_xor(m, off, 64));
      m = fmaxf(m, sz);
      float e = __expf(zi - m);
      float s = e;
      #pragma unroll
      for (int off = 32; off; off >>= 1) s += __shfl_xor(s, off, 64);
      float esz = __expf(sz - m);
      float denom = s + esz;
      wL[tid] = e/denom;
      if (tid == 0) wL[64] = esz/denom;
    }
    __syncthreads();
    // ---- F: attended + new h (tid<128) ----
    if (tid < 128){
      int j = tid;
      float a0 = 0.f, a1 = 0.f;
      #pragma unroll 4
      for (int n = 0; n < 64; ++n){
        float2 v = *(const float2*)&VL[n*256 + 2*j];
        float wn = wL[n];
        a0 += v.x*wn; a1 += v.y*wn;
      }
      float beta = wL[64];
      float ctx0 = (1.f - beta)*a0, ctx1 = (1.f - beta)*a1;
      ctxs0 += ctx0; ctxs1 += ctx1;
      float h0 = beta*sentL[2*j] + ctx0 + hnewL[2*j];
      float h1 = beta*sentL[2*j+1] + ctx1 + hnewL[2*j+1];
      hL[2*j] = h0; hL[2*j+1] = h1;
      __half2 ph = __floats2half2_rn(h0, h1); hP[j] = *(unsigned*)&ph;
    }
    __syncthreads();
  }
  // ---- epilogue: heads (only quarter 0 writes) ----
  if (q != 0) return;
  if (tid < 128){ ctxmL[2*tid] = ctxs0*(1.f/32.f); ctxmL[2*tid+1] = ctxs1*(1.f/32.f); }
  __syncthreads();
  if (tid < 256){
    float a = tob1[tid];
    const float* w = tow1 + (size_t)tid*256;
    #pragma unroll 4
    for (int c = 0; c < 256; ++c) a += hL[c]*w[c];
    tmpL[tid] = a > 0.f ? a : 0.f;
  }
  __syncthreads();
  if (tid < 128){
    float s = sob[tid];
    const float* w = sow + (size_t)tid*256;
    #pragma unroll 4
    for (int c = 0; c < 256; ++c) s += ctxmL[c]*w[c];
    out[b*128 + tid] = s;
    float tx = tob2[tid];
    const float* w2 = tow2 + (size_t)tid*256;
    #pragma unroll 4
    for (int k = 0; k < 256; ++k) tx += tmpL[k]*w2[k];
    out[8192 + b*128 + tid] = tx;
  }
}

extern "C" void kernel_launch(void* const* d_in, const int* in_sizes, int n_in,
                              void* d_out, int out_size, void* d_ws, size_t ws_size,
                              hipStream_t stream){
  const float* shape_in = (const float*)d_in[0];
  const int*   text_in  = (const int*)d_in[1];
  const float* c1w = (const float*)d_in[2];
  const float* c1b = (const float*)d_in[3];
  const float* g1  = (const float*)d_in[4];
  const float* be1 = (const float*)d_in[5];
  const float* c2w = (const float*)d_in[6];
  const float* c2b = (const float*)d_in[7];
  const float* g2  = (const float*)d_in[8];
  const float* be2 = (const float*)d_in[9];
  const float* c3w = (const float*)d_in[10];
  const float* c3b = (const float*)d_in[11];
  const float* g3  = (const float*)d_in[12];
  const float* be3 = (const float*)d_in[13];
  const float* sow = (const float*)d_in[14];
  const float* sob = (const float*)d_in[15];
  const float* emb = (const float*)d_in[16];
  const float* t1w = (const float*)d_in[17];
  const float* t1b = (const float*)d_in[18];
  const float* t2w = (const float*)d_in[19];
  const float* g128= (const float*)d_in[20];
  const float* b128= (const float*)d_in[21];
  const float* t3w = (const float*)d_in[22];
  const float* t3b = (const float*)d_in[23];
  const float* t4w = (const float*)d_in[24];
  const float* g256= (const float*)d_in[25];
  const float* b256= (const float*)d_in[26];
  const float* tow1= (const float*)d_in[27];
  const float* tob1= (const float*)d_in[28];
  const float* tow2= (const float*)d_in[29];
  const float* tob2= (const float*)d_in[30];
  const float* wih = (const float*)d_in[31];
  const float* whh = (const float*)d_in[32];
  const float* bih = (const float*)d_in[33];
  const float* bhh = (const float*)d_in[34];
  const float* wxg = (const float*)d_in[35];
  const float* bxg = (const float*)d_in[36];
  const float* whg = (const float*)d_in[37];
  const float* bhg = (const float*)d_in[38];
  const float* wv  = (const float*)d_in[39];
  const float* bv  = (const float*)d_in[40];
  const float* wh  = (const float*)d_in[41];
  const float* bh  = (const float*)d_in[42];
  const float* wsw = (const float*)d_in[43];
  const float* bsb = (const float*)d_in[44];
  const float* wo  = (const float*)d_in[45];
  const float* bo  = (const float*)d_in[46];
  float* out = (float*)d_out;
  float* Wk = (float*)d_ws;

  if (ws_size < (size_t)24905088*4) return;

  float* x1     = Wk + 0;            // dead after conv2
  float* xih    = Wk + 0;            // reuses x1 region
  float* xg     = Wk + 2097152;
  unsigned* vprojH = (unsigned*)(Wk + 2621440);   // 1,048,576 u32
  float* wT3_   = Wk + 4718592;      // written after conv2 (x1 dead)
  float* x2     = Wk + 16777216;     // dead after conv3
  float* wT1_   = Wk + 16777216;     // dead before conv2 writes x2
  float* exch1  = Wk + 16777216;     // 655,360 fl (scan only; x2 dead)
  float* Vb     = Wk + 20971520;
  float* wT2_   = Wk + 20971520;     // dead before conv3 writes Vb
  float* tE     = Wk + 22020096;
  unsigned* cnts = (unsigned*)(Wk + 22020096);    // 4096 u32 (tE dead by scan time)
  float* tA     = Wk + 22282240;
  float* tB     = Wk + 22544384;
  float* tC     = Wk + 22806528;
  float* tD     = Wk + 23330816;
  uint4* WA_    = (uint4*)(Wk + 23855104);
  uint4* WG_    = (uint4*)(Wk + 23986176);
  uint4* WC_    = (uint4*)(Wk + 24018944);
  float* wvT_   = Wk + 24444928;
  float* wihT_  = Wk + 24576000;
  float* wxgT_  = Wk + 24838144;
  float* scale1 = Wk + 24903680;
  float* shift1 = scale1 + 64;
  float* scale2 = shift1 + 64;
  float* shift2 = scale2 + 128;
  float* scale3 = shift2 + 128;
  float* shift3 = scale3 + 256;
  float* sums   = shift3 + 256;

  // scan weight packs (f16x8) + fp32 transposes
  k_packw8<<<128,256,0,stream>>>(WA_, whh, 1024, 256, 1024, 0);
  k_packw8<<<32, 256,0,stream>>>(WG_, whg, 256, 256, 256, 0);
  k_packw8<<<64, 256,0,stream>>>(WC_, wh,  512, 256, 1024, 0);
  k_packw8<<<64, 256,0,stream>>>(WC_, wsw, 512, 256, 1024, 512);
  k_transpose<<<512, 256,0,stream>>>(wvT_,  wv,  512, 256);
  k_transpose<<<1024,256,0,stream>>>(wihT_, wih, 1024, 256);
  k_transpose<<<256, 256,0,stream>>>(wxgT_, wxg, 256, 256);
  k_transpose<<<27,  256,0,stream>>>(wT1_,  c1w, 64, 108);
  k_transpose<<<864, 256,0,stream>>>(wT2_,  c2w, 128, 1728);

  // text branch
  k_embed<<<1024,256,0,stream>>>(tE, emb, text_in);
  k_conv1d<<<dim3(2,64),256,0,stream>>>(tE, t1w, t1b, tA, 128, 128);
  k_conv1d<<<dim3(2,64),256,0,stream>>>(tA, t2w, nullptr, tB, 128, 128);
  k_bn_text<<<128,256,0,stream>>>(tB, g128, b128, 128);
  k_conv1d<<<dim3(4,64),256,0,stream>>>(tB, t3w, t3b, tC, 128, 256);
  k_conv1d<<<dim3(4,64),256,0,stream>>>(tC, t4w, nullptr, tD, 256, 256);
  k_bn_text<<<256,256,0,stream>>>(tD, g256, b256, 256);

  // conv1 + bn1 stats
  k_conv1<<<dim3(16,4,64),256,0,stream>>>(shape_in, wT1_, c1b, x1);
  hipMemsetAsync(sums, 0, 2*64*sizeof(float), stream);
  k_bn_partial<<<64*16,256,0,stream>>>(x1, sums, 64, 4096, 16);
  k_bn_finalize<<<1,64,0,stream>>>(sums, g1, be1, scale1, shift1, 64, 4096);

  // conv2 + bn2 stats
  k_conv2<<<dim3(8,2,64),256,0,stream>>>(x1, wT2_, c2b, scale1, shift1, x2);
  hipMemsetAsync(sums, 0, 2*128*sizeof(float), stream);
  k_bn_partial<<<128*8,256,0,stream>>>(x2, sums, 128, 512, 8);
  k_bn_finalize<<<2,64,0,stream>>>(sums, g2, be2, scale2, shift2, 128, 512);

  // x-projections (x1 region now dead -> xih/xg)
  k_xproj<<<256,256,0,stream>>>(tD, wihT_, wxgT_, bih, bhh, bxg, bhg, xih, xg);

  // conv3 weight layout, then conv3 + bn3
  k_transpose<<<3456,256,0,stream>>>(wT3_, c3w, 256, 3456);
  k_conv3<<<dim3(8,64),256,0,stream>>>(x2, wT3_, c3b, scale2, shift2, Vb);
  hipMemsetAsync(sums, 0, 2*256*sizeof(float), stream);
  k_bn_partial<<<256*2,256,0,stream>>>(Vb, sums, 256, 64, 2);
  k_bn_finalize<<<4,64,0,stream>>>(sums, g3, be3, scale3, shift3, 256, 64);
  k_bn_apply<<<4096,256,0,stream>>>(Vb, scale3, shift3);

  // vproj (f16 packed)
  k_vproj<<<dim3(8,64),256,0,stream>>>(Vb, wvT_, bv, vprojH);

  // zero sync counters, then 4-way split scan + fused heads
  hipMemsetAsync(cnts, 0, 4096*sizeof(unsigned), stream);
  k_scan4<<<256,1024,0,stream>>>(Vb, vprojH, xih, xg, WA_, WG_, WC_,
                                 bh, bsb, wo, bo, sow, sob, tow1, tob1, tow2, tob2,
                                 exch1, cnts, out);
}

// Round 9
// 1477.555 us; speedup vs baseline: 1.5145x; 1.5145x over previous
//
#include <hip/hip_runtime.h>
#include <hip/hip_fp16.h>
#include <math.h>

#define EPSB 1e-5f

__device__ __forceinline__ float fsig(float x){ x = fminf(fmaxf(x,-30.f),30.f); return 1.f/(1.f+__expf(-x)); }
__device__ __forceinline__ float ftanh(float x){ x = fminf(fmaxf(x,-15.f),15.f); float t = __expf(2.f*x); return __fdividef(t-1.f, t+1.f); }

typedef _Float16 h2_t __attribute__((ext_vector_type(2)));
__device__ __forceinline__ h2_t as_h2(unsigned u){ union{unsigned x; h2_t h;} c; c.x=u; return c.h; }
__device__ __forceinline__ float dot2f(unsigned w, unsigned h, float acc){
#if __has_builtin(__builtin_amdgcn_fdot2)
  return __builtin_amdgcn_fdot2(as_h2(w), as_h2(h), acc, false);
#else
  __half2 hw = *(__half2*)&w, hh = *(__half2*)&h;
  return acc + __low2float(hw)*__low2float(hh) + __high2float(hw)*__high2float(hh);
#endif
}
__device__ __forceinline__ float2 h2f2(unsigned u){ __half2 h = *(__half2*)&u; return __half22float2(h); }
__device__ __forceinline__ unsigned packh2(float a, float b){ __half2 h = __floats2half2_rn(a,b); return *(unsigned*)&h; }

// agent-scope (LLC-coherent) helpers; all RELAXED (R5: release fence => L2 wbinv).
__device__ __forceinline__ void ag_store(float* p, float v){
  __hip_atomic_store(p, v, __ATOMIC_RELAXED, __HIP_MEMORY_SCOPE_AGENT);
}
__device__ __forceinline__ float ag_load(const float* p){
  return __hip_atomic_load(p, __ATOMIC_RELAXED, __HIP_MEMORY_SCOPE_AGENT);
}

// ---------------- transpose: dst[c*R+r] = src[r*C+c] ----------------
__global__ __launch_bounds__(256) void k_transpose(float* __restrict__ dst, const float* __restrict__ src, int R, int C){
  int t = blockIdx.x*256 + threadIdx.x;
  if (t >= R*C) return;
  int r = t / C, c = t - r*C;
  dst[c*R + r] = src[t];
}

// ---------------- pack fp32 [N][K] (out-major) -> f16x8 uint4 [K/8][dstStride] ----------------
__global__ __launch_bounds__(256) void k_packw8(uint4* __restrict__ dst, const float* __restrict__ src,
    int N, int K, int dstStride, int colOff){
  int t = blockIdx.x*256 + threadIdx.x;
  int total = N*(K >> 3);
  if (t >= total) return;
  int o = t % N, k8 = t / N;
  const float* s = src + (size_t)o*K + 8*k8;
  unsigned r[4];
  #pragma unroll
  for (int q = 0; q < 4; ++q) r[q] = packh2(s[2*q], s[2*q+1]);
  dst[(size_t)k8*dstStride + colOff + o] = make_uint4(r[0], r[1], r[2], r[3]);
}

// ---------------- pack conv weights fp32 [Co][Ci][27] -> u32 f16-ci-pair [(ci2*27+tap)][Co] ----------------
__global__ __launch_bounds__(256) void k_packwc(unsigned* __restrict__ dst, const float* __restrict__ src, int Co, int Ci){
  int t = blockIdx.x*256 + threadIdx.x;
  int total = Co*(Ci >> 1)*27;
  if (t >= total) return;
  int co = t % Co, r = t / Co;        // r = ci2*27 + tap
  int ci2 = r / 27, tap = r - ci2*27;
  float a = src[((size_t)co*Ci + 2*ci2)*27 + tap];
  float b = src[((size_t)co*Ci + 2*ci2 + 1)*27 + tap];
  dst[(size_t)r*Co + co] = packh2(a, b);
}

// ---------------- embedding ----------------
__global__ __launch_bounds__(256) void k_embed(float* __restrict__ tE, const float* __restrict__ emb, const int* __restrict__ idx){
  int t = blockIdx.x*256 + threadIdx.x;
  int b = t >> 12, r = t & 4095, ch = r >> 5, l = r & 31;
  tE[t] = emb[idx[b*32 + l]*128 + ch];
}

// ---------------- text conv1d (k=3, pad=1) + relu ----------------
__global__ __launch_bounds__(256) void k_conv1d(const float* __restrict__ in, const float* __restrict__ w,
    const float* __restrict__ bias, float* __restrict__ out, int Cin, int Cout){
  __shared__ float inL[8192];
  int b = blockIdx.y, tid = threadIdx.x;
  int n = Cin*32;
  for (int i = tid; i < n; i += 256) inL[i] = in[(size_t)b*n + i];
  __syncthreads();
  int u = blockIdx.x*256 + tid;
  int co = u >> 2, l0 = (u & 3)*8;
  float acc[8];
  #pragma unroll
  for (int l = 0; l < 8; ++l) acc[l] = 0.f;
  for (int ci = 0; ci < Cin; ++ci){
    float rin[10];
    #pragma unroll
    for (int ii = 0; ii < 10; ++ii){
      int p = l0 - 1 + ii;
      rin[ii] = (p >= 0 && p < 32) ? inL[ci*32 + p] : 0.f;
    }
    const float* wp = w + ((size_t)co*Cin + ci)*3;
    float w0 = wp[0], w1 = wp[1], w2 = wp[2];
    #pragma unroll
    for (int l = 0; l < 8; ++l) acc[l] += rin[l]*w0 + rin[l+1]*w1 + rin[l+2]*w2;
  }
  float bb = bias ? bias[co] : 0.f;
  #pragma unroll
  for (int l = 0; l < 8; ++l){
    float v = acc[l] + bb;
    out[((size_t)b*Cout + co)*32 + l0 + l] = v > 0.f ? v : 0.f;
  }
}

// ---------------- text bn ----------------
__global__ __launch_bounds__(256) void k_bn_text(float* __restrict__ x, const float* __restrict__ g, const float* __restrict__ be, int C){
  __shared__ float s1[256], s2[256];
  __shared__ float sc[2];
  int c = blockIdx.x, tid = threadIdx.x;
  float sum = 0.f, ss = 0.f;
  for (int i = tid; i < 2048; i += 256){
    int b = i >> 5, l = i & 31;
    float v = x[((size_t)b*C + c)*32 + l];
    sum += v; ss += v*v;
  }
  s1[tid] = sum; s2[tid] = ss;
  __syncthreads();
  for (int off = 128; off; off >>= 1){
    if (tid < off){ s1[tid] += s1[tid+off]; s2[tid] += s2[tid+off]; }
    __syncthreads();
  }
  if (tid == 0){
    float mean = s1[0]*(1.f/2048.f);
    float var  = s2[0]*(1.f/2048.f) - mean*mean;
    float rs = rsqrtf(var + EPSB);
    sc[0] = g[c]*rs;
    sc[1] = be[c] - mean*g[c]*rs;
  }
  __syncthreads();
  float a = sc[0], bsh = sc[1];
  for (int i = tid; i < 2048; i += 256){
    int b = i >> 5, l = i & 31;
    size_t o = ((size_t)b*C + c)*32 + l;
    x[o] = x[o]*a + bsh;
  }
}

// ---------------- bn partial over f16-pair tensor xh [64][C/2][S] ----------------
__global__ __launch_bounds__(256) void k_bn_partial_h(const unsigned* __restrict__ xh, float* __restrict__ sums, int C, int S, int split){
  __shared__ float s1[256], s2[256];
  int c = blockIdx.x / split, chunk = blockIdx.x - c*split;
  int tid = threadIdx.x;
  int n = 64*S, per = n/split, i0 = chunk*per;
  int c2 = c >> 1, hi = c & 1;
  float sum = 0.f, ss = 0.f;
  for (int i = i0 + tid; i < i0 + per; i += 256){
    int b = i / S, s = i - b*S;
    unsigned u = xh[((size_t)b*(C>>1) + c2)*S + s];
    float2 f = h2f2(u);
    float v = hi ? f.y : f.x;
    sum += v; ss += v*v;
  }
  s1[tid] = sum; s2[tid] = ss;
  __syncthreads();
  for (int off = 128; off; off >>= 1){
    if (tid < off){ s1[tid] += s1[tid+off]; s2[tid] += s2[tid+off]; }
    __syncthreads();
  }
  if (tid == 0){
    atomicAdd(&sums[c], s1[0]);
    atomicAdd(&sums[C + c], s2[0]);
  }
}

// ---------------- conv bn partial (fp32) + finalize ----------------
__global__ __launch_bounds__(256) void k_bn_partial(const float* __restrict__ x, float* __restrict__ sums, int C, int S, int split){
  __shared__ float s1[256], s2[256];
  int c = blockIdx.x / split, chunk = blockIdx.x - c*split;
  int tid = threadIdx.x;
  int n = 64*S, per = n/split, i0 = chunk*per;
  float sum = 0.f, ss = 0.f;
  for (int i = i0 + tid; i < i0 + per; i += 256){
    int b = i / S, s = i - b*S;
    float v = x[((size_t)b*C + c)*S + s];
    sum += v; ss += v*v;
  }
  s1[tid] = sum; s2[tid] = ss;
  __syncthreads();
  for (int off = 128; off; off >>= 1){
    if (tid < off){ s1[tid] += s1[tid+off]; s2[tid] += s2[tid+off]; }
    __syncthreads();
  }
  if (tid == 0){
    atomicAdd(&sums[c], s1[0]);
    atomicAdd(&sums[C + c], s2[0]);
  }
}

__global__ void k_bn_finalize(const float* __restrict__ sums, const float* __restrict__ g, const float* __restrict__ be,
    float* __restrict__ scale, float* __restrict__ shift, int C, int S){
  int c = blockIdx.x*64 + threadIdx.x;
  if (c >= C) return;
  float n = 64.f*(float)S;
  float mean = sums[c]/n;
  float var  = sums[C+c]/n - mean*mean;
  float rs = rsqrtf(var + EPSB);
  scale[c] = g[c]*rs;
  shift[c] = be[c] - mean*g[c]*rs;
}

// ---------------- conv1: fp32 math, writes f16 ci-pair packed x1h [b][co2=32][16][256] ----------------
__global__ __launch_bounds__(256) void k_conv1(const float* __restrict__ in, const float* __restrict__ wT1,
    const float* __restrict__ bias, unsigned* __restrict__ outh){
  __shared__ float tile[3888];
  int z = blockIdx.x, yq = blockIdx.y, b = blockIdx.z, tid = threadIdx.x;
  int cog = tid & 15, posg = tid >> 4;
  int yy = posg >> 2, xq = posg & 3;
  for (int i = tid; i < 3564; i += 256){
    int r = i/33, col = i - r*33;
    int ci = r/27, rr = r - 27*ci, dz = rr/9, iyl = rr - 9*dz;
    int iz = 2*z - 1 + dz;
    int iy = 8*yq - 1 + iyl;
    int ix = (col < 16) ? 2*col : 2*(col-16)-1;
    float v = 0.f;
    if (iz >= 0 && iz < 32 && iy >= 0 && ix >= 0)
      v = in[(((size_t)b*4 + ci)*32 + iz)*1024 + iy*32 + ix];
    tile[r*36 + col] = v;
  }
  __syncthreads();
  float acc[4][4];
  #pragma unroll
  for (int c = 0; c < 4; ++c){
    #pragma unroll
    for (int x = 0; x < 4; ++x) acc[c][x] = 0.f;
  }
  #pragma unroll 1
  for (int ci = 0; ci < 4; ++ci){
    #pragma unroll
    for (int dz = 0; dz < 3; ++dz){
      #pragma unroll
      for (int dy = 0; dy < 3; ++dy){
        int row = ci*972 + dz*324 + (2*yy + dy)*36;
        float4 ev = *(const float4*)&tile[row + 4*xq];
        float4 od = *(const float4*)&tile[row + 16 + 4*xq];
        float od4 = tile[row + 20 + 4*xq];
        const float* wp = wT1 + (ci*27 + dz*9 + dy*3)*64 + 4*cog;
        float4 w0 = *(const float4*)(wp);
        float4 w1 = *(const float4*)(wp + 64);
        float4 w2 = *(const float4*)(wp + 128);
        float iv0[4] = {od.x, od.y, od.z, od.w};
        float iv1[4] = {ev.x, ev.y, ev.z, ev.w};
        float iv2[4] = {od.y, od.z, od.w, od4};
        float wa0[4] = {w0.x,w0.y,w0.z,w0.w};
        float wa1[4] = {w1.x,w1.y,w1.z,w1.w};
        float wa2[4] = {w2.x,w2.y,w2.z,w2.w};
        #pragma unroll
        for (int c = 0; c < 4; ++c){
          #pragma unroll
          for (int x = 0; x < 4; ++x)
            acc[c][x] += wa0[c]*iv0[x] + wa1[c]*iv1[x] + wa2[c]*iv2[x];
        }
      }
    }
  }
  float4 bi = *(const float4*)&bias[4*cog];
  float ba[4] = {bi.x,bi.y,bi.z,bi.w};
  int y = yq*4 + yy;
  #pragma unroll
  for (int p = 0; p < 2; ++p){
    uint4 o; unsigned* op = (unsigned*)&o;
    #pragma unroll
    for (int x = 0; x < 4; ++x){
      float v0 = acc[2*p][x]   + ba[2*p];   v0 = v0 > 0.f ? v0 : 0.f;
      float v1 = acc[2*p+1][x] + ba[2*p+1]; v1 = v1 > 0.f ? v1 : 0.f;
      op[x] = packh2(v0, v1);
    }
    int co2 = 2*cog + p;
    *(uint4*)&outh[(((size_t)b*32 + co2)*16 + z)*256 + y*16 + 4*xq] = o;
  }
}

// ---------------- conv2: f16-pair dot2 path; reads x1h, writes x2h [b][co2=64][8][64] ----------------
__global__ __launch_bounds__(256) void k_conv2(const unsigned* __restrict__ x1h, const unsigned* __restrict__ wT2h,
    const float* __restrict__ bias, const float* __restrict__ scale, const float* __restrict__ shift,
    unsigned* __restrict__ outh){
  __shared__ unsigned tileU[8160];    // 8ci2 * 3dz * 17iy * 20
  __shared__ float sclL[64], shfL[64];
  int z = blockIdx.x, coh = blockIdx.y, b = blockIdx.z, tid = threadIdx.x;
  int cog = tid & 15, posg = tid >> 4;
  int y = posg >> 1, xq = posg & 1;
  if (tid < 64){ sclL[tid] = scale[tid]; shfL[tid] = shift[tid]; }
  float acc[4][4];
  #pragma unroll
  for (int c = 0; c < 4; ++c){
    #pragma unroll
    for (int x = 0; x < 4; ++x) acc[c][x] = 0.f;
  }
  for (int ci20 = 0; ci20 < 32; ci20 += 8){
    __syncthreads();
    for (int i = tid; i < 6936; i += 256){
      int q = i/289, rem = i - q*289;
      int iyr = rem/17, col = rem - iyr*17;
      int ci2 = q/3, dz = q - 3*ci2;
      int iz = 2*z - 1 + dz;
      int iy = iyr - 1;
      int ix = (col < 8) ? 2*col : 2*(col-8)-1;
      int cc2 = ci20 + ci2;
      unsigned v = 0u;
      if (iz >= 0 && iz < 16 && iy >= 0 && ix >= 0){
        unsigned u = x1h[(((size_t)b*32 + cc2)*16 + iz)*256 + iy*16 + ix];
        float2 f = h2f2(u);
        f.x = f.x*sclL[2*cc2]   + shfL[2*cc2];
        f.y = f.y*sclL[2*cc2+1] + shfL[2*cc2+1];
        v = packh2(f.x, f.y);
      }
      tileU[q*340 + iyr*20 + col] = v;
    }
    __syncthreads();
    #pragma unroll 1
    for (int ci2 = 0; ci2 < 8; ++ci2){
      const unsigned* wp = wT2h + ((size_t)(ci20+ci2)*27)*128 + coh*64 + 4*cog;
      #pragma unroll
      for (int dz = 0; dz < 3; ++dz){
        #pragma unroll
        for (int dy = 0; dy < 3; ++dy){
          int row = ci2*1020 + dz*340 + (2*y + dy)*20;
          uint4 ev = *(const uint4*)&tileU[row + 4*xq];
          uint4 od = *(const uint4*)&tileU[row + 8 + 4*xq];
          unsigned od4 = tileU[row + 12 + 4*xq];
          const unsigned* wq = wp + (dz*9 + dy*3)*128;
          uint4 w0 = *(const uint4*)(wq);
          uint4 w1 = *(const uint4*)(wq + 128);
          uint4 w2 = *(const uint4*)(wq + 256);
          unsigned iv0[4] = {od.x, od.y, od.z, od.w};
          unsigned iv1[4] = {ev.x, ev.y, ev.z, ev.w};
          unsigned iv2[4] = {od.y, od.z, od.w, od4};
          unsigned wa0[4] = {w0.x,w0.y,w0.z,w0.w};
          unsigned wa1[4] = {w1.x,w1.y,w1.z,w1.w};
          unsigned wa2[4] = {w2.x,w2.y,w2.z,w2.w};
          #pragma unroll
          for (int c = 0; c < 4; ++c){
            #pragma unroll
            for (int x = 0; x < 4; ++x){
              float a = acc[c][x];
              a = dot2f(wa0[c], iv0[x], a);
              a = dot2f(wa1[c], iv1[x], a);
              a = dot2f(wa2[c], iv2[x], a);
              acc[c][x] = a;
            }
          }
        }
      }
    }
  }
  float4 bi = *(const float4*)&bias[coh*64 + 4*cog];
  float ba[4] = {bi.x,bi.y,bi.z,bi.w};
  #pragma unroll
  for (int p = 0; p < 2; ++p){
    uint4 o; unsigned* op = (unsigned*)&o;
    #pragma unroll
    for (int x = 0; x < 4; ++x){
      float v0 = acc[2*p][x]   + ba[2*p];   v0 = v0 > 0.f ? v0 : 0.f;
      float v1 = acc[2*p+1][x] + ba[2*p+1]; v1 = v1 > 0.f ? v1 : 0.f;
      op[x] = packh2(v0, v1);
    }
    int co2 = coh*32 + 2*cog + p;
    *(uint4*)&outh[(((size_t)b*64 + co2)*8 + z)*64 + y*8 + 4*xq] = o;
  }
}

// ---------------- conv3: f16-pair dot2; reads x2h, writes Vb fp32 ----------------
__global__ __launch_bounds__(256) void k_conv3(const unsigned* __restrict__ x2h, const unsigned* __restrict__ wT3h,
    const float* __restrict__ bias, const float* __restrict__ scale, const float* __restrict__ shift,
    float* __restrict__ out){
  __shared__ unsigned tileU[7776];    // 8ci2 * 9iz * 9iy * 12
  __shared__ float sclL[128], shfL[128];
  int coq = blockIdx.x, b = blockIdx.y, tid = threadIdx.x;
  int cog = tid & 7, posg = tid >> 3;
  int zz = posg >> 3, y = (posg >> 1) & 3, xh = posg & 1;
  if (tid < 128){ sclL[tid] = scale[tid]; shfL[tid] = shift[tid]; }
  float acc[4][2];
  #pragma unroll
  for (int c = 0; c < 4; ++c){ acc[c][0] = 0.f; acc[c][1] = 0.f; }
  for (int ci20 = 0; ci20 < 64; ci20 += 8){
    __syncthreads();
    for (int i = tid; i < 5832; i += 256){
      int ci2 = i/729, rem = i - ci2*729;
      int izr = rem/81, rem2 = rem - izr*81;
      int iyr = rem2/9, col = rem2 - iyr*9;
      int iz = izr - 1, iy = iyr - 1;
      int ix = (col < 4) ? 2*col : 2*(col-4)-1;
      int cc2 = ci20 + ci2;
      unsigned v = 0u;
      if (iz >= 0 && iy >= 0 && ix >= 0){
        unsigned u = x2h[(((size_t)b*64 + cc2)*8 + iz)*64 + iy*8 + ix];
        float2 f = h2f2(u);
        f.x = f.x*sclL[2*cc2]   + shfL[2*cc2];
        f.y = f.y*sclL[2*cc2+1] + shfL[2*cc2+1];
        v = packh2(f.x, f.y);
      }
      tileU[ci2*972 + izr*108 + iyr*12 + col] = v;
    }
    __syncthreads();
    #pragma unroll 1
    for (int ci2 = 0; ci2 < 8; ++ci2){
      const unsigned* wp = wT3h + ((size_t)(ci20+ci2)*27)*256 + coq*32 + 4*cog;
      #pragma unroll
      for (int dz = 0; dz < 3; ++dz){
        #pragma unroll
        for (int dy = 0; dy < 3; ++dy){
          int row = ci2*972 + (2*zz + dz)*108 + (2*y + dy)*12;
          uint2 ev = *(const uint2*)&tileU[row + 2*xh];
          uint2 od = *(const uint2*)&tileU[row + 4 + 2*xh];
          unsigned od1 = tileU[row + 6 + 2*xh];
          const unsigned* wq = wp + (dz*9 + dy*3)*256;
          uint4 w0 = *(const uint4*)(wq);
          uint4 w1 = *(const uint4*)(wq + 256);
          uint4 w2 = *(const uint4*)(wq + 512);
          unsigned iv0[2] = {od.x, od.y};
          unsigned iv1[2] = {ev.x, ev.y};
          unsigned iv2[2] = {od.y, od1};
          unsigned wa0[4] = {w0.x,w0.y,w0.z,w0.w};
          unsigned wa1[4] = {w1.x,w1.y,w1.z,w1.w};
          unsigned wa2[4] = {w2.x,w2.y,w2.z,w2.w};
          #pragma unroll
          for (int c = 0; c < 4; ++c){
            #pragma unroll
            for (int x = 0; x < 2; ++x){
              float a = acc[c][x];
              a = dot2f(wa0[c], iv0[x], a);
              a = dot2f(wa1[c], iv1[x], a);
              a = dot2f(wa2[c], iv2[x], a);
              acc[c][x] = a;
            }
          }
        }
      }
    }
  }
  float4 bi = *(const float4*)&bias[coq*32 + 4*cog];
  float ba[4] = {bi.x,bi.y,bi.z,bi.w};
  #pragma unroll
  for (int c = 0; c < 4; ++c){
    int co = coq*32 + 4*cog + c;
    float2 o;
    float v0 = acc[c][0] + ba[c], v1 = acc[c][1] + ba[c];
    o.x = v0 > 0.f ? v0 : 0.f;
    o.y = v1 > 0.f ? v1 : 0.f;
    *(float2*)&out[((size_t)b*256 + co)*64 + zz*16 + y*4 + 2*xh] = o;
  }
}

// ---------------- bn3 apply ----------------
__global__ __launch_bounds__(256) void k_bn_apply(float* __restrict__ x, const float* __restrict__ scale, const float* __restrict__ shift){
  int i = blockIdx.x*256 + threadIdx.x;
  int c = (i >> 6) & 255;
  x[i] = x[i]*scale[c] + shift[c];
}

// ---------------- x-projections ----------------
__global__ __launch_bounds__(256) void k_xproj(const float* __restrict__ tD,
    const float* __restrict__ wihT, const float* __restrict__ wxgT,
    const float* __restrict__ bih, const float* __restrict__ bhh,
    const float* __restrict__ bxg, const float* __restrict__ bhg,
    float* __restrict__ xih, float* __restrict__ xg){
  __shared__ float xr[8][256];
  int b = blockIdx.x >> 2, t0 = (blockIdx.x & 3)*8, tid = threadIdx.x;
  for (int i = tid; i < 2048; i += 256){
    int tt = i >> 8, c = i & 255;
    xr[tt][c] = tD[((size_t)b*256 + c)*32 + t0 + tt];
  }
  __syncthreads();
  float4 bi = ((const float4*)bih)[tid];
  float4 b2 = ((const float4*)bhh)[tid];
  float4 binit = make_float4(bi.x+b2.x, bi.y+b2.y, bi.z+b2.z, bi.w+b2.w);
  float4 a[8];
  #pragma unroll
  for (int tt = 0; tt < 8; ++tt) a[tt] = binit;
  const float4* Wq = (const float4*)wihT;
  for (int k = 0; k < 256; ++k){
    float4 w = Wq[k*256 + tid];
    #pragma unroll
    for (int tt = 0; tt < 8; ++tt){
      float xv = xr[tt][k];
      a[tt].x += xv*w.x; a[tt].y += xv*w.y; a[tt].z += xv*w.z; a[tt].w += xv*w.w;
    }
  }
  #pragma unroll
  for (int tt = 0; tt < 8; ++tt)
    ((float4*)xih)[((size_t)(b*32 + t0 + tt))*256 + tid] = a[tt];
  if (tid < 64){
    float4 bg = ((const float4*)bxg)[tid];
    float4 bg2 = ((const float4*)bhg)[tid];
    float4 ginit = make_float4(bg.x+bg2.x, bg.y+bg2.y, bg.z+bg2.z, bg.w+bg2.w);
    float4 g[8];
    #pragma unroll
    for (int tt = 0; tt < 8; ++tt) g[tt] = ginit;
    const float4* Wg = (const float4*)wxgT;
    for (int k = 0; k < 256; ++k){
      float4 w = Wg[k*64 + tid];
      #pragma unroll
      for (int tt = 0; tt < 8; ++tt){
        float xv = xr[tt][k];
        g[tt].x += xv*w.x; g[tt].y += xv*w.y; g[tt].z += xv*w.z; g[tt].w += xv*w.w;
      }
    }
    #pragma unroll
    for (int tt = 0; tt < 8; ++tt)
      ((float4*)xg)[((size_t)(b*32 + t0 + tt))*64 + tid] = g[tt];
  }
}

// ---------------- vproj (f16 output) ----------------
__global__ __launch_bounds__(256) void k_vproj(const float* __restrict__ V, const float* __restrict__ wvT,
    const float* __restrict__ bv, unsigned* __restrict__ vprojH){
  __shared__ float Vc[8][256];
  int n0 = blockIdx.x*8, b = blockIdx.y, tid = threadIdx.x;
  for (int i = tid; i < 2048; i += 256){
    int nn = i >> 8, c = i & 255;
    Vc[nn][c] = V[((size_t)b*256 + c)*64 + n0 + nn];
  }
  __syncthreads();
  int o0 = 2*tid;
  float2 bb = *(const float2*)&bv[o0];
  float a0[8], a1[8];
  #pragma unroll
  for (int nn = 0; nn < 8; ++nn){ a0[nn] = bb.x; a1[nn] = bb.y; }
  for (int k = 0; k < 256; ++k){
    float2 w = *(const float2*)&wvT[k*512 + o0];
    #pragma unroll
    for (int nn = 0; nn < 8; ++nn){
      float vv = Vc[nn][k];
      a0[nn] += vv*w.x; a1[nn] += vv*w.y;
    }
  }
  #pragma unroll
  for (int nn = 0; nn < 8; ++nn)
    vprojH[((size_t)(b*64 + n0 + nn))*256 + tid] = packh2(a0[nn], a1[nn]);
}

// ---------------- 4-way K-split scan, XCD-aware q, vproj in LDS, 1 sync/step ----------------
__global__ __launch_bounds__(1024) void k_scan4(
    const float* __restrict__ V,
    const unsigned* __restrict__ vprojH,
    const float* __restrict__ xih,
    const float* __restrict__ xg,
    const uint4* __restrict__ WA,   // whh f16x8 [32][1024]
    const uint4* __restrict__ WG,   // whg f16x8 [32][256]
    const uint4* __restrict__ WC,   // wh | ws f16x8 [32][1024]
    const float* __restrict__ bh,
    const float* __restrict__ bs,
    const float* __restrict__ wo,
    const float* __restrict__ bo,
    const float* __restrict__ sow, const float* __restrict__ sob,
    const float* __restrict__ tow1, const float* __restrict__ tob1,
    const float* __restrict__ tow2, const float* __restrict__ tob2,
    float* __restrict__ exch1,      // [64][2][4][1280]
    unsigned* __restrict__ cnts,    // [64][32][2] (slot 0 used)
    float* __restrict__ out)
{
  __shared__ float VL[16384];
  __shared__ unsigned vprojL[16640];
  __shared__ __align__(16) float gatesL[1024];
  __shared__ float hgL[256];
  __shared__ float hL[256], hnewL[256], sentL[256];
  __shared__ __align__(16) unsigned hP[128];
  __shared__ __align__(16) unsigned hsP[256];
  __shared__ float hpSw[528], spSw[528], woSw[528];
  __shared__ float bhbsL[1024];
  __shared__ float red[1040];
  __shared__ float szred[576];
  __shared__ float wL[65];
  __shared__ float ctxmL[256], tmpL[256];

  int bid = blockIdx.x;
  int b = bid >> 2, q = bid & 3;       // XCD-aware: q constant per XCD
  int tid = threadIdx.x;
  int k80 = q*8;

  for (int i = tid; i < 16384; i += 1024){
    int c = i >> 6, n2 = i & 63;
    VL[n2*256 + c] = V[((size_t)b*256 + c)*64 + n2];
  }
  for (int i = tid; i < 16384; i += 1024)
    vprojL[(i >> 8)*260 + (i & 255)] = vprojH[(size_t)b*16384 + i];
  if (tid < 512) woSw[(tid>>5)*33 + (tid&31)] = wo[tid];
  bhbsL[tid] = (tid < 512) ? bh[tid] : bs[tid-512];
  if (tid < 128) hP[tid] = 0u;
  float creg0 = 0.f, creg1 = 0.f, ctxs0 = 0.f, ctxs1 = 0.f;
  float bo0 = bo[0];
  __syncthreads();

  for (int t = 0; t < 32; ++t){
    int par = t & 1;
    float* e1 = exch1 + (((size_t)b*2 + par)*4 + q)*1280;
    unsigned* c1 = cnts + (b*32 + t)*2;

    float mineGates, mineG = 0.f;
    {
      float a0 = 0.f, a1 = 0.f, a2 = 0.f, a3 = 0.f;
      #pragma unroll
      for (int i = 0; i < 8; ++i){
        uint4 w = WA[(size_t)(k80+i)*1024 + tid];
        uint4 hh = *(const uint4*)&hP[4*(k80+i)];
        a0 = dot2f(w.x, hh.x, a0);
        a1 = dot2f(w.y, hh.y, a1);
        a2 = dot2f(w.z, hh.z, a2);
        a3 = dot2f(w.w, hh.w, a3);
      }
      mineGates = (a0+a1)+(a2+a3);
      ag_store(&e1[tid], mineGates);
    }
    if (tid < 256){
      float g0 = 0.f, g1 = 0.f, g2 = 0.f, g3 = 0.f;
      #pragma unroll
      for (int i = 0; i < 8; ++i){
        uint4 w = WG[(size_t)(k80+i)*256 + tid];
        uint4 hh = *(const uint4*)&hP[4*(k80+i)];
        g0 = dot2f(w.x, hh.x, g0);
        g1 = dot2f(w.y, hh.y, g1);
        g2 = dot2f(w.z, hh.z, g2);
        g3 = dot2f(w.w, hh.w, g3);
      }
      mineG = (g0+g1)+(g2+g3);
      ag_store(&e1[1024 + tid], mineG);
    }
    __syncthreads();
    if (tid == 0){
      __hip_atomic_fetch_add(c1, 1u, __ATOMIC_RELAXED, __HIP_MEMORY_SCOPE_AGENT);
      while (__hip_atomic_load(c1, __ATOMIC_RELAXED, __HIP_MEMORY_SCOPE_AGENT) < 4u)
        __builtin_amdgcn_s_sleep(2);
    }
    __syncthreads();
    {
      const float* basep = exch1 + (((size_t)b*2 + par)*4)*1280;
      float s = xih[((size_t)(b*32 + t))*1024 + tid] + mineGates;
      #pragma unroll
      for (int qq = 0; qq < 4; ++qq){
        if (qq == q) continue;
        s += ag_load(basep + qq*1280 + tid);
      }
      gatesL[tid] = s;
      if (tid < 256){
        float g = xg[((size_t)(b*32 + t))*256 + tid] + mineG;
        #pragma unroll
        for (int qq = 0; qq < 4; ++qq){
          if (qq == q) continue;
          g += ag_load(basep + qq*1280 + 1024 + tid);
        }
        hgL[tid] = g;
      }
    }
    __syncthreads();
    if (tid < 128){
      int j = tid;
      float hg0 = hgL[2*j], hg1 = hgL[2*j+1];
      const float2* gl = (const float2*)gatesL;
      float2 gi = gl[j], gf = gl[128+j], gg = gl[256+j], go = gl[384+j];
      float i0 = fsig(gi.x), i1 = fsig(gi.y);
      float f0 = fsig(gf.x), f1 = fsig(gf.y);
      float g0 = ftanh(gg.x), g1 = ftanh(gg.y);
      float o0 = fsig(go.x), o1 = fsig(go.y);
      float c0 = f0*creg0 + i0*g0; creg0 = c0;
      float c1v = f1*creg1 + i1*g1; creg1 = c1v;
      float tc0 = ftanh(c0), tc1 = ftanh(c1v);
      float hn0 = o0*tc0, hn1 = o1*tc1;
      float s0 = fsig(hg0)*tc0, s1 = fsig(hg1)*tc1;
      hnewL[2*j] = hn0; hnewL[2*j+1] = hn1;
      sentL[2*j] = s0;  sentL[2*j+1] = s1;
      hsP[j] = packh2(hn0, hn1);
      hsP[128+j] = packh2(s0, s1);
    }
    __syncthreads();
    {
      int o = tid;
      int base = (o < 512) ? 0 : 128;
      float a0 = bhbsL[o], a1 = 0.f, a2 = 0.f, a3 = 0.f;
      #pragma unroll 8
      for (int k8 = 0; k8 < 32; ++k8){
        uint4 w = WC[(size_t)k8*1024 + o];
        uint4 hh = *(const uint4*)&hsP[base + 4*k8];
        a0 = dot2f(w.x, hh.x, a0);
        a1 = dot2f(w.y, hh.y, a1);
        a2 = dot2f(w.z, hh.z, a2);
        a3 = dot2f(w.w, hh.w, a3);
      }
      float acc = (a0+a1)+(a2+a3);
      int oo = o & 511;
      int r = (oo>>5)*33 + (oo&31);
      if (o < 512) hpSw[r] = acc; else spSw[r] = acc;
    }
    __syncthreads();
    {
      int n2 = tid >> 4, seg = tid & 15;
      const unsigned* vp = &vprojL[n2*260 + seg*16];
      float a = 0.f;
      #pragma unroll
      for (int qq = 0; qq < 4; ++qq){
        uint4 v = *(const uint4*)&vp[4*qq];
        int r = seg*33 + 8*qq;
        float2 f0 = h2f2(v.x), f1 = h2f2(v.y), f2 = h2f2(v.z), f3 = h2f2(v.w);
        a += ftanh(f0.x + hpSw[r  ])*woSw[r  ];
        a += ftanh(f0.y + hpSw[r+1])*woSw[r+1];
        a += ftanh(f1.x + hpSw[r+2])*woSw[r+2];
        a += ftanh(f1.y + hpSw[r+3])*woSw[r+3];
        a += ftanh(f2.x + hpSw[r+4])*woSw[r+4];
        a += ftanh(f2.y + hpSw[r+5])*woSw[r+5];
        a += ftanh(f3.x + hpSw[r+6])*woSw[r+6];
        a += ftanh(f3.y + hpSw[r+7])*woSw[r+7];
      }
      red[seg*65 + n2] = a;
      if (tid < 512){
        int r = (tid>>5)*33 + (tid&31);
        szred[(tid&63)*9 + (tid>>6)] = ftanh(spSw[r] + hpSw[r])*woSw[r];
      }
    }
    __syncthreads();
    if (tid < 64){
      float zi = bo0;
      #pragma unroll
      for (int i = 0; i < 16; ++i) zi += red[i*65 + tid];
      float szp = 0.f;
      #pragma unroll
      for (int i = 0; i < 8; ++i) szp += szred[tid*9 + i];
      #pragma unroll
      for (int off = 32; off; off >>= 1) szp += __shfl_xor(szp, off, 64);
      float sz = szp + bo0;
      float m = zi;
      #pragma unroll
      for (int off = 32; off; off >>= 1) m = fmaxf(m, __shfl_xor(m, off, 64));
      m = fmaxf(m, sz);
      float e = __expf(zi - m);
      float s = e;
      #pragma unroll
      for (int off = 32; off; off >>= 1) s += __shfl_xor(s, off, 64);
      float esz = __expf(sz - m);
      float denom = s + esz;
      wL[tid] = e/denom;
      if (tid == 0) wL[64] = esz/denom;
    }
    __syncthreads();
    if (tid < 128){
      int j = tid;
      float a0 = 0.f, a1 = 0.f;
      #pragma unroll 4
      for (int n = 0; n < 64; ++n){
        float2 v = *(const float2*)&VL[n*256 + 2*j];
        float wn = wL[n];
        a0 += v.x*wn; a1 += v.y*wn;
      }
      float beta = wL[64];
      float ctx0 = (1.f - beta)*a0, ctx1 = (1.f - beta)*a1;
      ctxs0 += ctx0; ctxs1 += ctx1;
      float h0 = beta*sentL[2*j] + ctx0 + hnewL[2*j];
      float h1 = beta*sentL[2*j+1] + ctx1 + hnewL[2*j+1];
      hL[2*j] = h0; hL[2*j+1] = h1;
      hP[j] = packh2(h0, h1);
    }
    __syncthreads();
  }
  if (q != 0) return;
  if (tid < 128){ ctxmL[2*tid] = ctxs0*(1.f/32.f); ctxmL[2*tid+1] = ctxs1*(1.f/32.f); }
  __syncthreads();
  if (tid < 256){
    float a = tob1[tid];
    const float* w = tow1 + (size_t)tid*256;
    #pragma unroll 4
    for (int c = 0; c < 256; ++c) a += hL[c]*w[c];
    tmpL[tid] = a > 0.f ? a : 0.f;
  }
  __syncthreads();
  if (tid < 128){
    float s = sob[tid];
    const float* w = sow + (size_t)tid*256;
    #pragma unroll 4
    for (int c = 0; c < 256; ++c) s += ctxmL[c]*w[c];
    out[b*128 + tid] = s;
    float tx = tob2[tid];
    const float* w2 = tow2 + (size_t)tid*256;
    #pragma unroll 4
    for (int k = 0; k < 256; ++k) tx += tmpL[k]*w2[k];
    out[8192 + b*128 + tid] = tx;
  }
}

extern "C" void kernel_launch(void* const* d_in, const int* in_sizes, int n_in,
                              void* d_out, int out_size, void* d_ws, size_t ws_size,
                              hipStream_t stream){
  const float* shape_in = (const float*)d_in[0];
  const int*   text_in  = (const int*)d_in[1];
  const float* c1w = (const float*)d_in[2];
  const float* c1b = (const float*)d_in[3];
  const float* g1  = (const float*)d_in[4];
  const float* be1 = (const float*)d_in[5];
  const float* c2w = (const float*)d_in[6];
  const float* c2b = (const float*)d_in[7];
  const float* g2  = (const float*)d_in[8];
  const float* be2 = (const float*)d_in[9];
  const float* c3w = (const float*)d_in[10];
  const float* c3b = (const float*)d_in[11];
  const float* g3  = (const float*)d_in[12];
  const float* be3 = (const float*)d_in[13];
  const float* sow = (const float*)d_in[14];
  const float* sob = (const float*)d_in[15];
  const float* emb = (const float*)d_in[16];
  const float* t1w = (const float*)d_in[17];
  const float* t1b = (const float*)d_in[18];
  const float* t2w = (const float*)d_in[19];
  const float* g128= (const float*)d_in[20];
  const float* b128= (const float*)d_in[21];
  const float* t3w = (const float*)d_in[22];
  const float* t3b = (const float*)d_in[23];
  const float* t4w = (const float*)d_in[24];
  const float* g256= (const float*)d_in[25];
  const float* b256= (const float*)d_in[26];
  const float* tow1= (const float*)d_in[27];
  const float* tob1= (const float*)d_in[28];
  const float* tow2= (const float*)d_in[29];
  const float* tob2= (const float*)d_in[30];
  const float* wih = (const float*)d_in[31];
  const float* whh = (const float*)d_in[32];
  const float* bih = (const float*)d_in[33];
  const float* bhh = (const float*)d_in[34];
  const float* wxg = (const float*)d_in[35];
  const float* bxg = (const float*)d_in[36];
  const float* whg = (const float*)d_in[37];
  const float* bhg = (const float*)d_in[38];
  const float* wv  = (const float*)d_in[39];
  const float* bv  = (const float*)d_in[40];
  const float* wh  = (const float*)d_in[41];
  const float* bh  = (const float*)d_in[42];
  const float* wsw = (const float*)d_in[43];
  const float* bsb = (const float*)d_in[44];
  const float* wo  = (const float*)d_in[45];
  const float* bo  = (const float*)d_in[46];
  float* out = (float*)d_out;
  float* Wk = (float*)d_ws;

  if (ws_size < (size_t)24905088*4) return;

  unsigned* x1h = (unsigned*)(Wk + 0);            // 8.4M u32 [b][32][16][256]; dead after conv2
  float* xih    = Wk + 0;                         // reuses x1h region (after conv2)
  float* xg     = Wk + 2097152;
  unsigned* vprojH = (unsigned*)(Wk + 2621440);   // 1,048,576 u32
  unsigned* wT3h = (unsigned*)(Wk + 4718592);     // 442,368 u32; packed AFTER conv2 (x1h dead)
  unsigned* x2h = (unsigned*)(Wk + 16777216);     // 2.1M u32 [b][64][8][64]
  float* wT1_   = Wk + 16777216;                  // dead before conv2 writes x2h
  float* exch1  = Wk + 16777216;                  // scan only; x2h dead then
  float* Vb     = Wk + 20971520;
  unsigned* wT2h = (unsigned*)(Wk + 20971520);    // 110,592 u32; dead before conv3 writes Vb
  float* tE     = Wk + 22020096;
  unsigned* cnts = (unsigned*)(Wk + 22020096);    // 4096 u32 (tE dead by scan time)
  float* tA     = Wk + 22282240;
  float* tB     = Wk + 22544384;
  float* tC     = Wk + 22806528;
  float* tD     = Wk + 23330816;
  uint4* WA_    = (uint4*)(Wk + 23855104);
  uint4* WG_    = (uint4*)(Wk + 23986176);
  uint4* WC_    = (uint4*)(Wk + 24018944);
  float* wvT_   = Wk + 24444928;
  float* wihT_  = Wk + 24576000;
  float* wxgT_  = Wk + 24838144;
  float* scale1 = Wk + 24903680;
  float* shift1 = scale1 + 64;
  float* scale2 = shift1 + 64;
  float* shift2 = scale2 + 128;
  float* scale3 = shift2 + 128;
  float* shift3 = scale3 + 256;
  float* sums   = shift3 + 256;

  // scan weight packs (f16x8) + transposes + conv weight f16-pair packs
  k_packw8<<<128,256,0,stream>>>(WA_, whh, 1024, 256, 1024, 0);
  k_packw8<<<32, 256,0,stream>>>(WG_, whg, 256, 256, 256, 0);
  k_packw8<<<64, 256,0,stream>>>(WC_, wh,  512, 256, 1024, 0);
  k_packw8<<<64, 256,0,stream>>>(WC_, wsw, 512, 256, 1024, 512);
  k_transpose<<<512, 256,0,stream>>>(wvT_,  wv,  512, 256);
  k_transpose<<<1024,256,0,stream>>>(wihT_, wih, 1024, 256);
  k_transpose<<<256, 256,0,stream>>>(wxgT_, wxg, 256, 256);
  k_transpose<<<27,  256,0,stream>>>(wT1_,  c1w, 64, 108);
  k_packwc<<<432, 256,0,stream>>>(wT2h, c2w, 128, 64);

  // text branch
  k_embed<<<1024,256,0,stream>>>(tE, emb, text_in);
  k_conv1d<<<dim3(2,64),256,0,stream>>>(tE, t1w, t1b, tA, 128, 128);
  k_conv1d<<<dim3(2,64),256,0,stream>>>(tA, t2w, nullptr, tB, 128, 128);
  k_bn_text<<<128,256,0,stream>>>(tB, g128, b128, 128);
  k_conv1d<<<dim3(4,64),256,0,stream>>>(tB, t3w, t3b, tC, 128, 256);
  k_conv1d<<<dim3(4,64),256,0,stream>>>(tC, t4w, nullptr, tD, 256, 256);
  k_bn_text<<<256,256,0,stream>>>(tD, g256, b256, 256);

  // conv1 (f16-pair output) + bn1 stats from f16
  k_conv1<<<dim3(16,4,64),256,0,stream>>>(shape_in, wT1_, c1b, x1h);
  hipMemsetAsync(sums, 0, 2*64*sizeof(float), stream);
  k_bn_partial_h<<<64*16,256,0,stream>>>(x1h, sums, 64, 4096, 16);
  k_bn_finalize<<<1,64,0,stream>>>(sums, g1, be1, scale1, shift1, 64, 4096);

  // conv2 (dot2 f16-pair) + bn2 stats
  k_conv2<<<dim3(8,2,64),256,0,stream>>>(x1h, wT2h, c2b, scale1, shift1, x2h);
  hipMemsetAsync(sums, 0, 2*128*sizeof(float), stream);
  k_bn_partial_h<<<128*8,256,0,stream>>>(x2h, sums, 128, 512, 8);
  k_bn_finalize<<<2,64,0,stream>>>(sums, g2, be2, scale2, shift2, 128, 512);

  // x-projections (x1h region now dead -> xih/xg)
  k_xproj<<<256,256,0,stream>>>(tD, wihT_, wxgT_, bih, bhh, bxg, bhg, xih, xg);

  // conv3 weight pack (into dead x1h region), then conv3 + bn3
  k_packwc<<<1728,256,0,stream>>>(wT3h, c3w, 256, 128);
  k_conv3<<<dim3(8,64),256,0,stream>>>(x2h, wT3h, c3b, scale2, shift2, Vb);
  hipMemsetAsync(sums, 0, 2*256*sizeof(float), stream);
  k_bn_partial<<<256*2,256,0,stream>>>(Vb, sums, 256, 64, 2);
  k_bn_finalize<<<4,64,0,stream>>>(sums, g3, be3, scale3, shift3, 256, 64);
  k_bn_apply<<<4096,256,0,stream>>>(Vb, scale3, shift3);

  // vproj (f16 packed)
  k_vproj<<<dim3(8,64),256,0,stream>>>(Vb, wvT_, bv, vprojH);

  // zero sync counters, then 4-way split scan + fused heads
  hipMemsetAsync(cnts, 0, 4096*sizeof(unsigned), stream);
  k_scan4<<<256,1024,0,stream>>>(Vb, vprojH, xih, xg, WA_, WG_, WC_,
                                 bh, bsb, wo, bo, sow, sob, tow1, tob1, tow2, tob2,
                                 exch1, cnts, out);
}